// Round 19
// baseline (353.918 us; speedup 1.0000x reference)
//
#include <hip/hip_runtime.h>
#include <hip/hip_bf16.h>
#include <hip/hip_fp16.h>

// Problem constants (fixed by reference setup_inputs)
#define NN 100000
#define NE 1600000
#define ET 1700000   // NE + NN self loops
#define NEG_SLOPE 0.2f
#define EPSI 1e-16f

#define SCAN_NB 98
#define DEG_PAD (SCAN_NB * 1024)   // 100352

// Workspace layout (4-byte element offsets). Total ~23.4 MB.
#define OFF_WF       0         // [32]
#define OFF_AS1      32        // [NN*4]
#define OFF_AD1      400032    // [NN*4]
#define OFF_AS2      800032    // [NN]
#define OFF_ADI      900032    // [NN float2: .x=ad2, .y=1/den2]  (byte 3600128, 8B aligned)
#define OFF_XW2H     1100032   // [NN*32 halfs = NN*16 floats]
#define OFF_OFFS     2700032   // [NN+1] int
#define OFF_RANK     2800034   // [ET ushort = 850000 floats]
#define OFF_EDATA    3650034   // [ET] int
#define OFF_POOLPART 5350036   // [12500*32] (byte 21400144, 8B aligned)
#define OFF_DEG      5750036   // [DEG_PAD] int (byte 23000144, 16B aligned) -- zero zone
#define OFF_POOL     5850388   // [64]
#define OFF_BSUM     5850452   // [112]
#define ZERO_START   OFF_DEG
#define ZERO_N4      ((DEG_PAD + 64) / 4)

__device__ __forceinline__ float lrelu(float v) { return v > 0.f ? v : NEG_SLOPE * v; }

__global__ void kz(float4* __restrict__ p, int n4) {
    int st = gridDim.x * 256;
    for (int i = blockIdx.x * 256 + threadIdx.x; i < n4; i += st)
        p[i] = make_float4(0.f, 0.f, 0.f, 0.f);
}

// K0: fold W1 with att vectors: wf[k*4+h] = sum_f W1[k,h*32+f]*a[h,f]
__global__ void k0_wfold(const float* __restrict__ W1, const float* __restrict__ aS1,
                         const float* __restrict__ aD1, float* __restrict__ wf) {
    int t = threadIdx.x;
    if (t < 32) {
        int u = t & 15, k = u >> 2, h = u & 3;
        const float* av = (t < 16) ? aS1 : aD1;
        float s = 0.f;
        for (int f = 0; f < 32; f++) s += W1[k * 128 + h * 32 + f] * av[h * 32 + f];
        wf[t] = s;
    }
}

// K1: as1[n,h] = x[n,:]@wf[:,h]; ad1 likewise
__global__ void k1_att1(const float* __restrict__ x, const float* __restrict__ wf,
                        float* __restrict__ as1, float* __restrict__ ad1) {
    int n = blockIdx.x * 256 + threadIdx.x;
    if (n >= NN) return;
    float4 xv = *(const float4*)(x + n * 4);
#pragma unroll
    for (int h = 0; h < 4; h++) {
        as1[n * 4 + h] = xv.x * wf[h] + xv.y * wf[4 + h] + xv.z * wf[8 + h] + xv.w * wf[12 + h];
        ad1[n * 4 + h] = xv.x * wf[16 + h] + xv.y * wf[20 + h] + xv.z * wf[24 + h] + xv.w * wf[28 + h];
    }
}

// CSR: degree histogram; atomic return value IS the edge's rank (max degree << 65536)
__global__ void kc1_deg(const int* __restrict__ ei, int* __restrict__ deg,
                        unsigned short* __restrict__ rank) {
    int e = blockIdx.x * 256 + threadIdx.x;
    if (e >= ET) return;
    int d_ = (e < NE) ? ei[NE + e] : (e - NE);
    rank[e] = (unsigned short)atomicAdd(&deg[d_], 1);
}

// Scan phase A: per-block (1024 elems) sums
__global__ void kc2a(const int* __restrict__ deg, int* __restrict__ bsum) {
    __shared__ int ws_[4];
    int b = blockIdx.x, t = threadIdx.x;
    int4 d = *(const int4*)(deg + b * 1024 + t * 4);
    int s = d.x + d.y + d.z + d.w;
#pragma unroll
    for (int m = 1; m < 64; m <<= 1) s += __shfl_xor(s, m);
    if ((t & 63) == 0) ws_[t >> 6] = s;
    __syncthreads();
    if (t == 0) bsum[b] = ws_[0] + ws_[1] + ws_[2] + ws_[3];
}

// Scan phase C: every block scans the 98 block sums, then intra-block
__global__ void kc2c(const int* __restrict__ deg, const int* __restrict__ bsum,
                     int* __restrict__ offs) {
    __shared__ int bs[128];
    __shared__ int ts[256];
    int b = blockIdx.x, t = threadIdx.x;
    if (t < 128) bs[t] = (t < SCAN_NB) ? bsum[t] : 0;
    __syncthreads();
    for (int off = 1; off < 128; off <<= 1) {
        int u = (t >= off && t < 128) ? bs[t - off] : 0;
        __syncthreads();
        if (t < 128) bs[t] += u;
        __syncthreads();
    }
    int bpre = (b == 0) ? 0 : bs[b - 1];
    int base = b * 1024 + t * 4;
    int4 d = *(const int4*)(deg + base);
    int s = d.x + d.y + d.z + d.w;
    ts[t] = s;
    __syncthreads();
    for (int off = 1; off < 256; off <<= 1) {
        int u = (t >= off) ? ts[t - off] : 0;
        __syncthreads();
        ts[t] += u;
        __syncthreads();
    }
    int r = bpre + ((t == 0) ? 0 : ts[t - 1]);
    if (base < NN)     offs[base] = r;     r += d.x;
    if (base + 1 < NN) offs[base + 1] = r; r += d.y;
    if (base + 2 < NN) offs[base + 2] = r; r += d.z;
    if (base + 3 < NN) offs[base + 3] = r;
    if (b == 0 && t == 0) offs[NN] = bs[SCAN_NB - 1];   // == ET
}

// CSR fill: NO atomic — position = offs[dst] + rank[e]
__global__ void kc3_fill(const int* __restrict__ ei, const int* __restrict__ offs,
                         const unsigned short* __restrict__ rank, int* __restrict__ edata) {
    int e = blockIdx.x * 256 + threadIdx.x;
    if (e >= ET) return;
    int s_, d_;
    if (e < NE) { s_ = ei[e]; d_ = ei[NE + e]; } else { s_ = d_ = e - NE; }
    edata[offs[d_] + (int)rank[e]] = s_;
}

// K4AB v2: 16 nodes/block, 4 nodes/wave. Gather: each 16-lane group owns one
// node (4-way edge split, shfl_xor width-16 reduce). Dense: one wq LDS read
// serves 4 nodes' FMAs (weight traffic and staging amortized 4x).
__global__ __launch_bounds__(256) void k4ab(
    const int* __restrict__ offs, const int* __restrict__ edata,
    const float* __restrict__ x, const float* __restrict__ as1,
    const float* __restrict__ ad1, const float* __restrict__ W1,
    const float* __restrict__ b1, const float* __restrict__ W2,
    const float* __restrict__ aw_s2, const float* __restrict__ aw_d2,
    __half* __restrict__ xw2h, float* __restrict__ as2, float* __restrict__ adi) {
    __shared__ float4 wq[32][32];           // wq[kq][f] = W2[4kq..4kq+3][f] (16 KB)
    __shared__ float hsf[4][4][128];        // [wave][node][k] (8 KB)
    int tid = threadIdx.x;
    int wv = tid >> 6, ln = tid & 63;
    int g = ln >> 4, q16 = ln & 15, hq = q16 & 3, p = q16 >> 2;
    int nbase = blockIdx.x * 16 + wv * 4;   // grid exact: 6250*16 = NN
    int ng = nbase + g;
    // ---- stage W2 quads into LDS (f-coalesced global reads) ----
    for (int idx = tid; idx < 1024; idx += 256) {
        int kq = idx >> 5, sf = idx & 31;
        int kb = kq * 4;
        wq[kq][sf] = make_float4(W2[(kb + 0) * 32 + sf], W2[(kb + 1) * 32 + sf],
                                 W2[(kb + 2) * 32 + sf], W2[(kb + 3) * 32 + sf]);
    }
    // ---- gather phase: group g gathers node ng (4-way edge split) ----
    float ad = ad1[ng * 4 + hq];
    float z0 = 0.f, z1 = 0.f, z2 = 0.f, z3 = 0.f, den = 0.f;
    int beg = offs[ng], end = offs[ng + 1];
    for (int j = beg + p; j < end; j += 4) {
        int src = edata[j];
        float ex = __expf(lrelu(as1[src * 4 + hq] + ad));
        float4 xv = *(const float4*)(x + src * 4);
        den += ex;
        z0 += ex * xv.x; z1 += ex * xv.y; z2 += ex * xv.z; z3 += ex * xv.w;
    }
#pragma unroll
    for (int m = 4; m <= 8; m <<= 1) {
        den += __shfl_xor(den, m, 16);
        z0 += __shfl_xor(z0, m, 16); z1 += __shfl_xor(z1, m, 16);
        z2 += __shfl_xor(z2, m, 16); z3 += __shfl_xor(z3, m, 16);
    }
    float inv = 1.f / (den + EPSI);
    float v0 = z0 * inv, v1 = z1 * inv, v2 = z2 * inv, v3 = z3 * inv;
    // lane (g, hq, any p) now holds msg[ng][hq][0..3]
    // ---- W1 + elu for all 4 nodes; lane owns cols f0=2ln, f0+1 (head = g) ----
    int f0 = ln * 2;
    float w10 = W1[f0],       w11 = W1[f0 + 1];
    float w20 = W1[128 + f0], w21 = W1[128 + f0 + 1];
    float w30 = W1[256 + f0], w31 = W1[256 + f0 + 1];
    float w40 = W1[384 + f0], w41 = W1[384 + f0 + 1];
    float bb0 = b1[f0], bb1 = b1[f0 + 1];
#pragma unroll
    for (int i = 0; i < 4; i++) {
        int sl = i * 16 + g;                // lane holding msg[nbase+i][head g]
        float mx = __shfl(v0, sl), my = __shfl(v1, sl);
        float mz = __shfl(v2, sl), mw = __shfl(v3, sl);
        float h0 = mx * w10 + my * w20 + mz * w30 + mw * w40 + bb0;
        float h1 = mx * w11 + my * w21 + mz * w31 + mw * w41 + bb1;
        h0 = h0 > 0.f ? h0 : (__expf(h0) - 1.f);
        h1 = h1 > 0.f ? h1 : (__expf(h1) - 1.f);
        *(float2*)(&hsf[wv][i][f0]) = make_float2(h0, h1);
    }
    __syncthreads();                        // covers wq staging + hsf
    // ---- dense: a_i[f] = sum_k h_i[k]*W2[k][f]; one wq read serves 4 nodes ----
    int f = ln & 31, kq0 = (ln >> 5) * 16;
    float a0[4] = {0.f, 0.f, 0.f, 0.f}, a1[4] = {0.f, 0.f, 0.f, 0.f};
#pragma unroll
    for (int q = 0; q < 16; q++) {
        float4 wv4 = wq[kq0 + q][f];        // contiguous: conflict-free
#pragma unroll
        for (int i = 0; i < 4; i++) {
            float4 hv = *(const float4*)(&hsf[wv][i][(kq0 + q) * 4]);  // broadcast
            a0[i] += hv.x * wv4.x + hv.y * wv4.y;
            a1[i] += hv.z * wv4.z + hv.w * wv4.w;
        }
    }
#pragma unroll
    for (int i = 0; i < 4; i++) {
        float a = a0[i] + a1[i];
        a += __shfl_xor(a, 32);             // combine k-halves
        float ps = a * aw_s2[f], pd = a * aw_d2[f];
#pragma unroll
        for (int m = 1; m <= 16; m <<= 1) { ps += __shfl_xor(ps, m); pd += __shfl_xor(pd, m); }
        if (ln < 32) xw2h[(nbase + i) * 32 + f] = __float2half_rn(a);
        if (ln == 0) { as2[nbase + i] = ps; adi[2 * (nbase + i)] = pd; }
    }
}

// K6: conv2 gather, edge-parallel, half2 payload; writes 1/den into adi[2n+1].
__global__ __launch_bounds__(256) void k6_conv2(
    const int* __restrict__ offs, const int* __restrict__ edata,
    const __half2* __restrict__ xw2h2, const float* __restrict__ as2,
    float* __restrict__ adi, const float* __restrict__ b2,
    float* __restrict__ pool_part) {
    __shared__ float2 psum[4][16];
    int sub = threadIdx.x >> 5, f = threadIdx.x & 31;
    int f2 = f & 15, g = f >> 4;
    int n = blockIdx.x * 8 + sub;           // grid exact: 12500*8 = NN
    float ad = adi[2 * n];
    float den = 0.f, accx = 0.f, accy = 0.f;
    int beg = offs[n], end = offs[n + 1];
    for (int base = beg; base < end; base += 32) {
        int j = base + f;
        int src = 0;
        float ex = 0.f;
        if (j < end) {
            src = edata[j];                          // coalesced
            ex = __expf(lrelu(as2[src] + ad));       // 32 exps in parallel
        }
        den += ex;
        int cnt = min(32, end - base);
        for (int k2 = 0; k2 < cnt; k2 += 2) {
            int ki = k2 + g;                         // group g takes edge k2+g
            int   sk = __shfl(src, ki, 32);
            float ek = __shfl(ex, ki, 32);
            if (ki < cnt) {                          // explicit tail guard
                float2 fv = __half22float2(xw2h2[sk * 16 + f2]);
                accx += ek * fv.x;
                accy += ek * fv.y;
            }
        }
    }
#pragma unroll
    for (int m = 1; m < 32; m <<= 1) den += __shfl_xor(den, m, 32);
    float inv = 1.f / (den + EPSI);
    if (f == 0) adi[2 * n + 1] = inv;
    // combine the two edge-groups (same features, disjoint edges)
    accx += __shfl_xor(accx, 16, 32);
    accy += __shfl_xor(accy, 16, 32);
    float vx = accx * inv + b2[2 * f2];
    float vy = accy * inv + b2[2 * f2 + 1];
    vx = vx > 0.f ? vx : (__expf(vx) - 1.f);
    vy = vy > 0.f ? vy : (__expf(vy) - 1.f);
    // combine the wave's two nodes
    vx += __shfl_xor(vx, 32);
    vy += __shfl_xor(vy, 32);
    int wv = threadIdx.x >> 6;
    if ((threadIdx.x & 63) < 16) psum[wv][f2] = make_float2(vx, vy);
    __syncthreads();
    if (threadIdx.x < 16) {
        float2 a0 = psum[0][threadIdx.x], a1 = psum[1][threadIdx.x];
        float2 a2 = psum[2][threadIdx.x], a3 = psum[3][threadIdx.x];
        ((float2*)pool_part)[blockIdx.x * 16 + threadIdx.x] =
            make_float2(a0.x + a1.x + a2.x + a3.x, a0.y + a1.y + a2.y + a3.y);
    }
}

// K7: attn in COO order; single float2 gather for (ad2, 1/den) per dst
__global__ void k7_attn(const int* __restrict__ ei, const float* __restrict__ as2,
                        const float* __restrict__ adi, float* __restrict__ attn) {
    int e = blockIdx.x * 256 + threadIdx.x;
    if (e >= ET) return;
    int s_, d_;
    if (e < NE) { s_ = ei[e]; d_ = ei[NE + e]; } else { s_ = d_ = e - NE; }
    float2 av = *(const float2*)(adi + 2 * d_);
    attn[e] = __expf(lrelu(as2[s_] + av.x)) * av.y;
}

// K8: reduce pool partials (elu+bias already applied in k6)
__global__ void k8_pool(const float* __restrict__ pool_part, float* __restrict__ pool) {
    int tid = threadIdx.x;
    int f = tid & 31;
    float acc = 0.f;
    int st = gridDim.x * 256;
    for (int i = blockIdx.x * 256 + tid; i < 12500 * 32; i += st) acc += pool_part[i];
    acc += __shfl_xor(acc, 32);
    if ((tid & 63) < 32) unsafeAtomicAdd(&pool[f], acc);
}

// K9: logits
__global__ void k9_logits(const float* __restrict__ pool, const float* __restrict__ lin_w,
                          const float* __restrict__ lin_b, float* __restrict__ out) {
    int j = threadIdx.x;
    if (j < 2) {
        float s = 0.f;
        for (int f = 0; f < 32; f++) s += (pool[f] * (1.0f / NN)) * lin_w[f * 2 + j];
        out[j] = s + lin_b[j];
    }
}

extern "C" void kernel_launch(void* const* d_in, const int* in_sizes, int n_in,
                              void* d_out, int out_size, void* d_ws, size_t ws_size,
                              hipStream_t stream) {
    const float* x    = (const float*)d_in[0];
    const int*   ei   = (const int*)d_in[1];
    const float* W1   = (const float*)d_in[2];
    const float* aS1  = (const float*)d_in[3];
    const float* aD1  = (const float*)d_in[4];
    const float* b1   = (const float*)d_in[5];
    const float* W2   = (const float*)d_in[6];
    const float* aS2  = (const float*)d_in[7];
    const float* aD2  = (const float*)d_in[8];
    const float* b2   = (const float*)d_in[9];
    const float* linw = (const float*)d_in[10];
    const float* linb = (const float*)d_in[11];

    float*          ws    = (float*)d_ws;
    float*          wf    = ws + OFF_WF;
    float*          as1   = ws + OFF_AS1;
    float*          ad1   = ws + OFF_AD1;
    float*          as2   = ws + OFF_AS2;
    float*          adi   = ws + OFF_ADI;
    __half*         xw2h  = (__half*)(ws + OFF_XW2H);
    int*            offs  = (int*)(ws + OFF_OFFS);
    unsigned short* rank  = (unsigned short*)(ws + OFF_RANK);
    int*            ed    = (int*)(ws + OFF_EDATA);
    float*          ppart = ws + OFF_POOLPART;
    int*            deg   = (int*)(ws + OFF_DEG);
    float*          pool  = ws + OFF_POOL;
    int*            bsum  = (int*)(ws + OFF_BSUM);

    float* logits = (float*)d_out;
    float* attn   = (float*)d_out + 2;

    kz<<<98, 256, 0, stream>>>((float4*)(ws + ZERO_START), ZERO_N4);
    k0_wfold<<<1, 64, 0, stream>>>(W1, aS1, aD1, wf);
    k1_att1<<<(NN + 255) / 256, 256, 0, stream>>>(x, wf, as1, ad1);
    kc1_deg<<<(ET + 255) / 256, 256, 0, stream>>>(ei, deg, rank);
    kc2a<<<SCAN_NB, 256, 0, stream>>>(deg, bsum);
    kc2c<<<SCAN_NB, 256, 0, stream>>>(deg, bsum, offs);
    kc3_fill<<<(ET + 255) / 256, 256, 0, stream>>>(ei, offs, rank, ed);
    k4ab<<<NN / 16, 256, 0, stream>>>(offs, ed, x, as1, ad1, W1, b1, W2,
                                      aS2, aD2, xw2h, as2, adi);
    k6_conv2<<<NN / 8, 256, 0, stream>>>(offs, ed, (const __half2*)xw2h, as2, adi,
                                         b2, ppart);
    k7_attn<<<(ET + 255) / 256, 256, 0, stream>>>(ei, as2, adi, attn);
    k8_pool<<<256, 256, 0, stream>>>(ppart, pool);
    k9_logits<<<1, 64, 0, stream>>>(pool, linw, linb, logits);
}

// Round 20
// 272.155 us; speedup vs baseline: 1.3004x; 1.3004x over previous
//
#include <hip/hip_runtime.h>
#include <hip/hip_bf16.h>
#include <hip/hip_fp16.h>

// Problem constants (fixed by reference setup_inputs)
#define NN 100000
#define NE 1600000
#define ET 1700000   // NE + NN self loops
#define NEG_SLOPE 0.2f
#define EPSI 1e-16f

#define SCAN_NB 98
#define DEG_PAD (SCAN_NB * 1024)   // 100352

// Workspace layout (4-byte element offsets). Total ~23.4 MB.
#define OFF_WF       0         // [32]
#define OFF_AS1      32        // [NN*4]
#define OFF_AD1      400032    // [NN*4]
#define OFF_AS2      800032    // [NN]
#define OFF_ADI      900032    // [NN float2: .x=ad2, .y=1/den2]  (byte 3600128, 8B aligned)
#define OFF_XW2H     1100032   // [NN*32 halfs = NN*16 floats]
#define OFF_OFFS     2700032   // [NN+1] int
#define OFF_RANK     2800034   // [ET ushort = 850000 floats]
#define OFF_EDATA    3650034   // [ET] int
#define OFF_POOLPART 5350036   // [12500*32] (byte 21400144, 8B aligned)
#define OFF_DEG      5750036   // [DEG_PAD] int (byte 23000144, 16B aligned) -- zero zone
#define OFF_POOL     5850388   // [64]
#define OFF_BSUM     5850452   // [112]
#define ZERO_START   OFF_DEG
#define ZERO_N4      ((DEG_PAD + 64) / 4)

__device__ __forceinline__ float lrelu(float v) { return v > 0.f ? v : NEG_SLOPE * v; }

__global__ void kz(float4* __restrict__ p, int n4) {
    int st = gridDim.x * 256;
    for (int i = blockIdx.x * 256 + threadIdx.x; i < n4; i += st)
        p[i] = make_float4(0.f, 0.f, 0.f, 0.f);
}

// K0: fold W1 with att vectors: wf[k*4+h] = sum_f W1[k,h*32+f]*a[h,f]
__global__ void k0_wfold(const float* __restrict__ W1, const float* __restrict__ aS1,
                         const float* __restrict__ aD1, float* __restrict__ wf) {
    int t = threadIdx.x;
    if (t < 32) {
        int u = t & 15, k = u >> 2, h = u & 3;
        const float* av = (t < 16) ? aS1 : aD1;
        float s = 0.f;
        for (int f = 0; f < 32; f++) s += W1[k * 128 + h * 32 + f] * av[h * 32 + f];
        wf[t] = s;
    }
}

// K1: as1[n,h] = x[n,:]@wf[:,h]; ad1 likewise
__global__ void k1_att1(const float* __restrict__ x, const float* __restrict__ wf,
                        float* __restrict__ as1, float* __restrict__ ad1) {
    int n = blockIdx.x * 256 + threadIdx.x;
    if (n >= NN) return;
    float4 xv = *(const float4*)(x + n * 4);
#pragma unroll
    for (int h = 0; h < 4; h++) {
        as1[n * 4 + h] = xv.x * wf[h] + xv.y * wf[4 + h] + xv.z * wf[8 + h] + xv.w * wf[12 + h];
        ad1[n * 4 + h] = xv.x * wf[16 + h] + xv.y * wf[20 + h] + xv.z * wf[24 + h] + xv.w * wf[28 + h];
    }
}

// CSR: degree histogram; atomic return value IS the edge's rank (max degree << 65536)
__global__ void kc1_deg(const int* __restrict__ ei, int* __restrict__ deg,
                        unsigned short* __restrict__ rank) {
    int e = blockIdx.x * 256 + threadIdx.x;
    if (e >= ET) return;
    int d_ = (e < NE) ? ei[NE + e] : (e - NE);
    rank[e] = (unsigned short)atomicAdd(&deg[d_], 1);
}

// Scan phase A: per-block (1024 elems) sums
__global__ void kc2a(const int* __restrict__ deg, int* __restrict__ bsum) {
    __shared__ int ws_[4];
    int b = blockIdx.x, t = threadIdx.x;
    int4 d = *(const int4*)(deg + b * 1024 + t * 4);
    int s = d.x + d.y + d.z + d.w;
#pragma unroll
    for (int m = 1; m < 64; m <<= 1) s += __shfl_xor(s, m);
    if ((t & 63) == 0) ws_[t >> 6] = s;
    __syncthreads();
    if (t == 0) bsum[b] = ws_[0] + ws_[1] + ws_[2] + ws_[3];
}

// Scan phase C: every block scans the 98 block sums, then intra-block
__global__ void kc2c(const int* __restrict__ deg, const int* __restrict__ bsum,
                     int* __restrict__ offs) {
    __shared__ int bs[128];
    __shared__ int ts[256];
    int b = blockIdx.x, t = threadIdx.x;
    if (t < 128) bs[t] = (t < SCAN_NB) ? bsum[t] : 0;
    __syncthreads();
    for (int off = 1; off < 128; off <<= 1) {
        int u = (t >= off && t < 128) ? bs[t - off] : 0;
        __syncthreads();
        if (t < 128) bs[t] += u;
        __syncthreads();
    }
    int bpre = (b == 0) ? 0 : bs[b - 1];
    int base = b * 1024 + t * 4;
    int4 d = *(const int4*)(deg + base);
    int s = d.x + d.y + d.z + d.w;
    ts[t] = s;
    __syncthreads();
    for (int off = 1; off < 256; off <<= 1) {
        int u = (t >= off) ? ts[t - off] : 0;
        __syncthreads();
        ts[t] += u;
        __syncthreads();
    }
    int r = bpre + ((t == 0) ? 0 : ts[t - 1]);
    if (base < NN)     offs[base] = r;     r += d.x;
    if (base + 1 < NN) offs[base + 1] = r; r += d.y;
    if (base + 2 < NN) offs[base + 2] = r; r += d.z;
    if (base + 3 < NN) offs[base + 3] = r;
    if (b == 0 && t == 0) offs[NN] = bs[SCAN_NB - 1];   // == ET
}

// CSR fill: NO atomic — position = offs[dst] + rank[e]
__global__ void kc3_fill(const int* __restrict__ ei, const int* __restrict__ offs,
                         const unsigned short* __restrict__ rank, int* __restrict__ edata) {
    int e = blockIdx.x * 256 + threadIdx.x;
    if (e >= ET) return;
    int s_, d_;
    if (e < NE) { s_ = ei[e]; d_ = ei[NE + e]; } else { s_ = d_ = e - NE; }
    edata[offs[d_] + (int)rank[e]] = s_;
}

// K4AB: fused conv1 gather + dense. W2 staged TRANSPOSED in LDS (thrash-immune,
// per-lane contiguous ds_read_b128; +4 row pad for bank spread). All fp32.
__global__ __launch_bounds__(256) void k4ab(
    const int* __restrict__ offs, const int* __restrict__ edata,
    const float* __restrict__ x, const float* __restrict__ as1,
    const float* __restrict__ ad1, const float* __restrict__ W1,
    const float* __restrict__ b1, const float* __restrict__ W2,
    const float* __restrict__ aw_s2, const float* __restrict__ aw_d2,
    __half* __restrict__ xw2h, float* __restrict__ as2, float* __restrict__ adi) {
    __shared__ float w2t[32][132];          // transposed W2, padded (16.9 KB)
    __shared__ float hs[4][128];
    int tid = threadIdx.x;
    int wv = tid >> 6, ln = tid & 63;
    int n = blockIdx.x * 4 + wv;            // grid exact: 25000*4 = NN
    // ---- stage W2^T into LDS (coalesced global reads; issued before gather) ----
    {
        int sf = tid & 31, sk0 = (tid >> 5) * 16;
#pragma unroll
        for (int j = 0; j < 16; j++)
            w2t[sf][sk0 + j] = W2[(sk0 + j) * 32 + sf];
    }
    // ---- gather phase ----
    int hq = ln & 3, p = ln >> 2;
    float ad = ad1[n * 4 + hq];
    float z0 = 0.f, z1 = 0.f, z2 = 0.f, z3 = 0.f, den = 0.f;
    int beg = offs[n], end = offs[n + 1];
    for (int j = beg + p; j < end; j += 16) {
        int src = edata[j];
        float ex = __expf(lrelu(as1[src * 4 + hq] + ad));
        float4 xv = *(const float4*)(x + src * 4);
        den += ex;
        z0 += ex * xv.x; z1 += ex * xv.y; z2 += ex * xv.z; z3 += ex * xv.w;
    }
#pragma unroll
    for (int m = 4; m <= 32; m <<= 1) {
        den += __shfl_xor(den, m);
        z0 += __shfl_xor(z0, m); z1 += __shfl_xor(z1, m);
        z2 += __shfl_xor(z2, m); z3 += __shfl_xor(z3, m);
    }
    float inv = 1.f / (den + EPSI);
    float v0 = z0 * inv, v1 = z1 * inv, v2 = z2 * inv, v3 = z3 * inv;
    // ---- W1 + elu (msg via shfl: head h lives in lane h) ----
    int f0 = ln * 2, h = ln >> 4;
    float mx = __shfl(v0, h), my = __shfl(v1, h), mz = __shfl(v2, h), mw = __shfl(v3, h);
    float h0 = mx * W1[f0]     + my * W1[128 + f0]     + mz * W1[256 + f0]     + mw * W1[384 + f0]     + b1[f0];
    float h1 = mx * W1[f0 + 1] + my * W1[128 + f0 + 1] + mz * W1[256 + f0 + 1] + mw * W1[384 + f0 + 1] + b1[f0 + 1];
    h0 = h0 > 0.f ? h0 : (__expf(h0) - 1.f);
    h1 = h1 > 0.f ? h1 : (__expf(h1) - 1.f);
    hs[wv][f0] = h0; hs[wv][f0 + 1] = h1;
    __syncthreads();                        // covers w2t staging + hs
    // ---- dense: a[f] = sum_k h[k]*W2[k][f]; half splits k; LDS b128 reads ----
    int f = ln & 31, kb = (ln >> 5) * 64;
    const float* hrow = &hs[wv][kb];
    const float* wrow = &w2t[f][kb];
    float a0 = 0.f, a1 = 0.f;
#pragma unroll
    for (int k = 0; k < 64; k += 4) {
        float4 hv  = *(const float4*)(hrow + k);
        float4 wv4 = *(const float4*)(wrow + k);
        a0 += hv.x * wv4.x + hv.y * wv4.y;
        a1 += hv.z * wv4.z + hv.w * wv4.w;
    }
    float a = a0 + a1;
    a += __shfl_xor(a, 32);
    float ps = a * aw_s2[f], pd = a * aw_d2[f];
#pragma unroll
    for (int m2 = 1; m2 < 32; m2 <<= 1) { ps += __shfl_xor(ps, m2); pd += __shfl_xor(pd, m2); }
    if (ln < 32) xw2h[n * 32 + f] = __float2half_rn(a);
    if (ln == 0) { as2[n] = ps; adi[2 * n] = pd; }
}

// K6: conv2 gather, edge-parallel, half2 payload; writes 1/den into adi[2n+1].
__global__ __launch_bounds__(256) void k6_conv2(
    const int* __restrict__ offs, const int* __restrict__ edata,
    const __half2* __restrict__ xw2h2, const float* __restrict__ as2,
    float* __restrict__ adi, const float* __restrict__ b2,
    float* __restrict__ pool_part) {
    __shared__ float2 psum[4][16];
    int sub = threadIdx.x >> 5, f = threadIdx.x & 31;
    int f2 = f & 15, g = f >> 4;
    int n = blockIdx.x * 8 + sub;           // grid exact: 12500*8 = NN
    float ad = adi[2 * n];
    float den = 0.f, accx = 0.f, accy = 0.f;
    int beg = offs[n], end = offs[n + 1];
    for (int base = beg; base < end; base += 32) {
        int j = base + f;
        int src = 0;
        float ex = 0.f;
        if (j < end) {
            src = edata[j];                          // coalesced
            ex = __expf(lrelu(as2[src] + ad));       // 32 exps in parallel
        }
        den += ex;
        int cnt = min(32, end - base);
        for (int k2 = 0; k2 < cnt; k2 += 2) {
            int ki = k2 + g;                         // group g takes edge k2+g
            int   sk = __shfl(src, ki, 32);
            float ek = __shfl(ex, ki, 32);
            if (ki < cnt) {                          // explicit tail guard
                float2 fv = __half22float2(xw2h2[sk * 16 + f2]);
                accx += ek * fv.x;
                accy += ek * fv.y;
            }
        }
    }
#pragma unroll
    for (int m = 1; m < 32; m <<= 1) den += __shfl_xor(den, m, 32);
    float inv = 1.f / (den + EPSI);
    if (f == 0) adi[2 * n + 1] = inv;
    // combine the two edge-groups (same features, disjoint edges)
    accx += __shfl_xor(accx, 16, 32);
    accy += __shfl_xor(accy, 16, 32);
    float vx = accx * inv + b2[2 * f2];
    float vy = accy * inv + b2[2 * f2 + 1];
    vx = vx > 0.f ? vx : (__expf(vx) - 1.f);
    vy = vy > 0.f ? vy : (__expf(vy) - 1.f);
    // combine the wave's two nodes
    vx += __shfl_xor(vx, 32);
    vy += __shfl_xor(vy, 32);
    int wv = threadIdx.x >> 6;
    if ((threadIdx.x & 63) < 16) psum[wv][f2] = make_float2(vx, vy);
    __syncthreads();
    if (threadIdx.x < 16) {
        float2 a0 = psum[0][threadIdx.x], a1 = psum[1][threadIdx.x];
        float2 a2 = psum[2][threadIdx.x], a3 = psum[3][threadIdx.x];
        ((float2*)pool_part)[blockIdx.x * 16 + threadIdx.x] =
            make_float2(a0.x + a1.x + a2.x + a3.x, a0.y + a1.y + a2.y + a3.y);
    }
}

// K7: attn in COO order; single float2 gather for (ad2, 1/den) per dst
__global__ void k7_attn(const int* __restrict__ ei, const float* __restrict__ as2,
                        const float* __restrict__ adi, float* __restrict__ attn) {
    int e = blockIdx.x * 256 + threadIdx.x;
    if (e >= ET) return;
    int s_, d_;
    if (e < NE) { s_ = ei[e]; d_ = ei[NE + e]; } else { s_ = d_ = e - NE; }
    float2 av = *(const float2*)(adi + 2 * d_);
    attn[e] = __expf(lrelu(as2[s_] + av.x)) * av.y;
}

// K8: reduce pool partials (elu+bias already applied in k6)
__global__ void k8_pool(const float* __restrict__ pool_part, float* __restrict__ pool) {
    int tid = threadIdx.x;
    int f = tid & 31;
    float acc = 0.f;
    int st = gridDim.x * 256;
    for (int i = blockIdx.x * 256 + tid; i < 12500 * 32; i += st) acc += pool_part[i];
    acc += __shfl_xor(acc, 32);
    if ((tid & 63) < 32) unsafeAtomicAdd(&pool[f], acc);
}

// K9: logits
__global__ void k9_logits(const float* __restrict__ pool, const float* __restrict__ lin_w,
                          const float* __restrict__ lin_b, float* __restrict__ out) {
    int j = threadIdx.x;
    if (j < 2) {
        float s = 0.f;
        for (int f = 0; f < 32; f++) s += (pool[f] * (1.0f / NN)) * lin_w[f * 2 + j];
        out[j] = s + lin_b[j];
    }
}

extern "C" void kernel_launch(void* const* d_in, const int* in_sizes, int n_in,
                              void* d_out, int out_size, void* d_ws, size_t ws_size,
                              hipStream_t stream) {
    const float* x    = (const float*)d_in[0];
    const int*   ei   = (const int*)d_in[1];
    const float* W1   = (const float*)d_in[2];
    const float* aS1  = (const float*)d_in[3];
    const float* aD1  = (const float*)d_in[4];
    const float* b1   = (const float*)d_in[5];
    const float* W2   = (const float*)d_in[6];
    const float* aS2  = (const float*)d_in[7];
    const float* aD2  = (const float*)d_in[8];
    const float* b2   = (const float*)d_in[9];
    const float* linw = (const float*)d_in[10];
    const float* linb = (const float*)d_in[11];

    float*          ws    = (float*)d_ws;
    float*          wf    = ws + OFF_WF;
    float*          as1   = ws + OFF_AS1;
    float*          ad1   = ws + OFF_AD1;
    float*          as2   = ws + OFF_AS2;
    float*          adi   = ws + OFF_ADI;
    __half*         xw2h  = (__half*)(ws + OFF_XW2H);
    int*            offs  = (int*)(ws + OFF_OFFS);
    unsigned short* rank  = (unsigned short*)(ws + OFF_RANK);
    int*            ed    = (int*)(ws + OFF_EDATA);
    float*          ppart = ws + OFF_POOLPART;
    int*            deg   = (int*)(ws + OFF_DEG);
    float*          pool  = ws + OFF_POOL;
    int*            bsum  = (int*)(ws + OFF_BSUM);

    float* logits = (float*)d_out;
    float* attn   = (float*)d_out + 2;

    kz<<<98, 256, 0, stream>>>((float4*)(ws + ZERO_START), ZERO_N4);
    k0_wfold<<<1, 64, 0, stream>>>(W1, aS1, aD1, wf);
    k1_att1<<<(NN + 255) / 256, 256, 0, stream>>>(x, wf, as1, ad1);
    kc1_deg<<<(ET + 255) / 256, 256, 0, stream>>>(ei, deg, rank);
    kc2a<<<SCAN_NB, 256, 0, stream>>>(deg, bsum);
    kc2c<<<SCAN_NB, 256, 0, stream>>>(deg, bsum, offs);
    kc3_fill<<<(ET + 255) / 256, 256, 0, stream>>>(ei, offs, rank, ed);
    k4ab<<<NN / 4, 256, 0, stream>>>(offs, ed, x, as1, ad1, W1, b1, W2,
                                     aS2, aD2, xw2h, as2, adi);
    k6_conv2<<<NN / 8, 256, 0, stream>>>(offs, ed, (const __half2*)xw2h, as2, adi,
                                         b2, ppart);
    k7_attn<<<(ET + 255) / 256, 256, 0, stream>>>(ei, as2, adi, attn);
    k8_pool<<<256, 256, 0, stream>>>(ppart, pool);
    k9_logits<<<1, 64, 0, stream>>>(pool, linw, linb, logits);
}

// Round 21
// 262.412 us; speedup vs baseline: 1.3487x; 1.0371x over previous
//
#include <hip/hip_runtime.h>
#include <hip/hip_bf16.h>
#include <hip/hip_fp16.h>

// Problem constants (fixed by reference setup_inputs)
#define NN 100000
#define NE 1600000
#define ET 1700000   // NE + NN self loops
#define NEG_SLOPE 0.2f
#define EPSI 1e-16f

#define SCAN_NB 98
#define DEG_PAD (SCAN_NB * 1024)   // 100352

// Workspace layout (4-byte element offsets). Total ~25 MB.
#define OFF_XA       32        // [NN*8] packed {x[4], as1[4]} rows (byte 128, 32B aligned)
#define OFF_AD1      800032    // [NN*4]
#define OFF_AS2      1200032   // [NN]
#define OFF_ADI      1300032   // [NN float2: .x=ad2, .y=1/den2] (byte 5200128, 8B aligned)
#define OFF_XW2H     1500032   // [NN*32 halfs = NN*16 floats]
#define OFF_OFFS     3100032   // [NN+1] int
#define OFF_RANK     3200034   // [ET ushort = 850000 floats]
#define OFF_EDATA    4050034   // [ET] int
#define OFF_POOLPART 5750036   // [12500*32] (8B aligned)
#define OFF_DEG      6150036   // [DEG_PAD] int (byte 24600144, 16B aligned) -- zero zone
#define OFF_POOL     6250388   // [64]
#define OFF_BSUM     6250452   // [112]
#define ZERO_START   OFF_DEG
#define ZERO_N4      ((DEG_PAD + 64) / 4)   // 25104 float4 (deg + pool)

__device__ __forceinline__ float lrelu(float v) { return v > 0.f ? v : NEG_SLOPE * v; }

// K1: per-block wf fold (tiny) + zero-slice of deg/pool + write packed xa + ad1.
__global__ __launch_bounds__(256) void k1_att1(
    const float* __restrict__ x, const float* __restrict__ W1,
    const float* __restrict__ aS1, const float* __restrict__ aD1,
    float* __restrict__ xa, float* __restrict__ ad1, float4* __restrict__ zz) {
    __shared__ float wfl[32];
    int t = threadIdx.x;
    if (t < 32) {   // wf[k*4+h]: fold W1 with att vectors (1024 FLOP/block, free)
        int u = t & 15, k = u >> 2, h = u & 3;
        const float* av = (t < 16) ? aS1 : aD1;
        float s = 0.f;
        for (int f = 0; f < 32; f++) s += W1[k * 128 + h * 32 + f] * av[h * 32 + f];
        wfl[t] = s;
    }
    __syncthreads();
    int gid = blockIdx.x * 256 + t;
    if (gid < ZERO_N4) zz[gid] = make_float4(0.f, 0.f, 0.f, 0.f);   // deg + pool
    int n = gid;
    if (n >= NN) return;
    float4 xv = *(const float4*)(x + n * 4);
    float* xr = xa + n * 8;
    *(float4*)xr = xv;
#pragma unroll
    for (int h = 0; h < 4; h++) {
        xr[4 + h] = xv.x * wfl[h] + xv.y * wfl[4 + h] + xv.z * wfl[8 + h] + xv.w * wfl[12 + h];
        ad1[n * 4 + h] = xv.x * wfl[16 + h] + xv.y * wfl[20 + h] + xv.z * wfl[24 + h] + xv.w * wfl[28 + h];
    }
}

// CSR: degree histogram; atomic return value IS the edge's rank (max degree << 65536)
__global__ void kc1_deg(const int* __restrict__ ei, int* __restrict__ deg,
                        unsigned short* __restrict__ rank) {
    int e = blockIdx.x * 256 + threadIdx.x;
    if (e >= ET) return;
    int d_ = (e < NE) ? ei[NE + e] : (e - NE);
    rank[e] = (unsigned short)atomicAdd(&deg[d_], 1);
}

// Scan phase A: per-block (1024 elems) sums
__global__ void kc2a(const int* __restrict__ deg, int* __restrict__ bsum) {
    __shared__ int ws_[4];
    int b = blockIdx.x, t = threadIdx.x;
    int4 d = *(const int4*)(deg + b * 1024 + t * 4);
    int s = d.x + d.y + d.z + d.w;
#pragma unroll
    for (int m = 1; m < 64; m <<= 1) s += __shfl_xor(s, m);
    if ((t & 63) == 0) ws_[t >> 6] = s;
    __syncthreads();
    if (t == 0) bsum[b] = ws_[0] + ws_[1] + ws_[2] + ws_[3];
}

// Scan phase C: every block scans the 98 block sums, then intra-block
__global__ void kc2c(const int* __restrict__ deg, const int* __restrict__ bsum,
                     int* __restrict__ offs) {
    __shared__ int bs[128];
    __shared__ int ts[256];
    int b = blockIdx.x, t = threadIdx.x;
    if (t < 128) bs[t] = (t < SCAN_NB) ? bsum[t] : 0;
    __syncthreads();
    for (int off = 1; off < 128; off <<= 1) {
        int u = (t >= off && t < 128) ? bs[t - off] : 0;
        __syncthreads();
        if (t < 128) bs[t] += u;
        __syncthreads();
    }
    int bpre = (b == 0) ? 0 : bs[b - 1];
    int base = b * 1024 + t * 4;
    int4 d = *(const int4*)(deg + base);
    int s = d.x + d.y + d.z + d.w;
    ts[t] = s;
    __syncthreads();
    for (int off = 1; off < 256; off <<= 1) {
        int u = (t >= off) ? ts[t - off] : 0;
        __syncthreads();
        ts[t] += u;
        __syncthreads();
    }
    int r = bpre + ((t == 0) ? 0 : ts[t - 1]);
    if (base < NN)     offs[base] = r;     r += d.x;
    if (base + 1 < NN) offs[base + 1] = r; r += d.y;
    if (base + 2 < NN) offs[base + 2] = r; r += d.z;
    if (base + 3 < NN) offs[base + 3] = r;
    if (b == 0 && t == 0) offs[NN] = bs[SCAN_NB - 1];   // == ET
}

// CSR fill: NO atomic — position = offs[dst] + rank[e]
__global__ void kc3_fill(const int* __restrict__ ei, const int* __restrict__ offs,
                         const unsigned short* __restrict__ rank, int* __restrict__ edata) {
    int e = blockIdx.x * 256 + threadIdx.x;
    if (e >= ET) return;
    int s_, d_;
    if (e < NE) { s_ = ei[e]; d_ = ei[NE + e]; } else { s_ = d_ = e - NE; }
    edata[offs[d_] + (int)rank[e]] = s_;
}

// K4AB: fused conv1 gather + dense. Gather reads packed xa rows (x + as1 in ONE
// 64B line per edge). W2 staged transposed in LDS (thrash-immune). All fp32.
__global__ __launch_bounds__(256) void k4ab(
    const int* __restrict__ offs, const int* __restrict__ edata,
    const float* __restrict__ xa, const float* __restrict__ ad1,
    const float* __restrict__ W1, const float* __restrict__ b1,
    const float* __restrict__ W2, const float* __restrict__ aw_s2,
    const float* __restrict__ aw_d2, __half* __restrict__ xw2h,
    float* __restrict__ as2, float* __restrict__ adi) {
    __shared__ float w2t[32][132];          // transposed W2, padded (16.9 KB)
    __shared__ float hs[4][128];
    int tid = threadIdx.x;
    int wv = tid >> 6, ln = tid & 63;
    int n = blockIdx.x * 4 + wv;            // grid exact: 25000*4 = NN
    // ---- stage W2^T into LDS (coalesced global reads; issued before gather) ----
    {
        int sf = tid & 31, sk0 = (tid >> 5) * 16;
#pragma unroll
        for (int j = 0; j < 16; j++)
            w2t[sf][sk0 + j] = W2[(sk0 + j) * 32 + sf];
    }
    // ---- gather phase (packed xa: one line per edge) ----
    int hq = ln & 3, p = ln >> 2;
    float ad = ad1[n * 4 + hq];
    float z0 = 0.f, z1 = 0.f, z2 = 0.f, z3 = 0.f, den = 0.f;
    int beg = offs[n], end = offs[n + 1];
    for (int j = beg + p; j < end; j += 16) {
        int src = edata[j];
        const float* xr = xa + src * 8;
        float4 xv = *(const float4*)xr;
        float ex = __expf(lrelu(xr[4 + hq] + ad));   // same 64B line as xv
        den += ex;
        z0 += ex * xv.x; z1 += ex * xv.y; z2 += ex * xv.z; z3 += ex * xv.w;
    }
#pragma unroll
    for (int m = 4; m <= 32; m <<= 1) {
        den += __shfl_xor(den, m);
        z0 += __shfl_xor(z0, m); z1 += __shfl_xor(z1, m);
        z2 += __shfl_xor(z2, m); z3 += __shfl_xor(z3, m);
    }
    float inv = 1.f / (den + EPSI);
    float v0 = z0 * inv, v1 = z1 * inv, v2 = z2 * inv, v3 = z3 * inv;
    // ---- W1 + elu (msg via shfl: head h lives in lane h) ----
    int f0 = ln * 2, h = ln >> 4;
    float mx = __shfl(v0, h), my = __shfl(v1, h), mz = __shfl(v2, h), mw = __shfl(v3, h);
    float h0 = mx * W1[f0]     + my * W1[128 + f0]     + mz * W1[256 + f0]     + mw * W1[384 + f0]     + b1[f0];
    float h1 = mx * W1[f0 + 1] + my * W1[128 + f0 + 1] + mz * W1[256 + f0 + 1] + mw * W1[384 + f0 + 1] + b1[f0 + 1];
    h0 = h0 > 0.f ? h0 : (__expf(h0) - 1.f);
    h1 = h1 > 0.f ? h1 : (__expf(h1) - 1.f);
    hs[wv][f0] = h0; hs[wv][f0 + 1] = h1;
    __syncthreads();                        // covers w2t staging + hs
    // ---- dense: a[f] = sum_k h[k]*W2[k][f]; half splits k; LDS b128 reads ----
    int f = ln & 31, kb = (ln >> 5) * 64;
    const float* hrow = &hs[wv][kb];
    const float* wrow = &w2t[f][kb];
    float a0 = 0.f, a1 = 0.f;
#pragma unroll
    for (int k = 0; k < 64; k += 4) {
        float4 hv  = *(const float4*)(hrow + k);
        float4 wv4 = *(const float4*)(wrow + k);
        a0 += hv.x * wv4.x + hv.y * wv4.y;
        a1 += hv.z * wv4.z + hv.w * wv4.w;
    }
    float a = a0 + a1;
    a += __shfl_xor(a, 32);
    float ps = a * aw_s2[f], pd = a * aw_d2[f];
#pragma unroll
    for (int m2 = 1; m2 < 32; m2 <<= 1) { ps += __shfl_xor(ps, m2); pd += __shfl_xor(pd, m2); }
    if (ln < 32) xw2h[n * 32 + f] = __float2half_rn(a);
    if (ln == 0) { as2[n] = ps; adi[2 * n] = pd; }
}

// K6: conv2 gather, edge-parallel, half2 payload; writes 1/den into adi[2n+1].
__global__ __launch_bounds__(256) void k6_conv2(
    const int* __restrict__ offs, const int* __restrict__ edata,
    const __half2* __restrict__ xw2h2, const float* __restrict__ as2,
    float* __restrict__ adi, const float* __restrict__ b2,
    float* __restrict__ pool_part) {
    __shared__ float2 psum[4][16];
    int sub = threadIdx.x >> 5, f = threadIdx.x & 31;
    int f2 = f & 15, g = f >> 4;
    int n = blockIdx.x * 8 + sub;           // grid exact: 12500*8 = NN
    float ad = adi[2 * n];
    float den = 0.f, accx = 0.f, accy = 0.f;
    int beg = offs[n], end = offs[n + 1];
    for (int base = beg; base < end; base += 32) {
        int j = base + f;
        int src = 0;
        float ex = 0.f;
        if (j < end) {
            src = edata[j];                          // coalesced
            ex = __expf(lrelu(as2[src] + ad));       // 32 exps in parallel
        }
        den += ex;
        int cnt = min(32, end - base);
        for (int k2 = 0; k2 < cnt; k2 += 2) {
            int ki = k2 + g;                         // group g takes edge k2+g
            int   sk = __shfl(src, ki, 32);
            float ek = __shfl(ex, ki, 32);
            if (ki < cnt) {                          // explicit tail guard
                float2 fv = __half22float2(xw2h2[sk * 16 + f2]);
                accx += ek * fv.x;
                accy += ek * fv.y;
            }
        }
    }
#pragma unroll
    for (int m = 1; m < 32; m <<= 1) den += __shfl_xor(den, m, 32);
    float inv = 1.f / (den + EPSI);
    if (f == 0) adi[2 * n + 1] = inv;
    // combine the two edge-groups (same features, disjoint edges)
    accx += __shfl_xor(accx, 16, 32);
    accy += __shfl_xor(accy, 16, 32);
    float vx = accx * inv + b2[2 * f2];
    float vy = accy * inv + b2[2 * f2 + 1];
    vx = vx > 0.f ? vx : (__expf(vx) - 1.f);
    vy = vy > 0.f ? vy : (__expf(vy) - 1.f);
    // combine the wave's two nodes
    vx += __shfl_xor(vx, 32);
    vy += __shfl_xor(vy, 32);
    int wv = threadIdx.x >> 6;
    if ((threadIdx.x & 63) < 16) psum[wv][f2] = make_float2(vx, vy);
    __syncthreads();
    if (threadIdx.x < 16) {
        float2 a0 = psum[0][threadIdx.x], a1 = psum[1][threadIdx.x];
        float2 a2 = psum[2][threadIdx.x], a3 = psum[3][threadIdx.x];
        ((float2*)pool_part)[blockIdx.x * 16 + threadIdx.x] =
            make_float2(a0.x + a1.x + a2.x + a3.x, a0.y + a1.y + a2.y + a3.y);
    }
}

// K7: attn in COO order; single float2 gather for (ad2, 1/den) per dst
__global__ void k7_attn(const int* __restrict__ ei, const float* __restrict__ as2,
                        const float* __restrict__ adi, float* __restrict__ attn) {
    int e = blockIdx.x * 256 + threadIdx.x;
    if (e >= ET) return;
    int s_, d_;
    if (e < NE) { s_ = ei[e]; d_ = ei[NE + e]; } else { s_ = d_ = e - NE; }
    float2 av = *(const float2*)(adi + 2 * d_);
    attn[e] = __expf(lrelu(as2[s_] + av.x)) * av.y;
}

// K8: reduce pool partials (elu+bias already applied in k6)
__global__ void k8_pool(const float* __restrict__ pool_part, float* __restrict__ pool) {
    int tid = threadIdx.x;
    int f = tid & 31;
    float acc = 0.f;
    int st = gridDim.x * 256;
    for (int i = blockIdx.x * 256 + tid; i < 12500 * 32; i += st) acc += pool_part[i];
    acc += __shfl_xor(acc, 32);
    if ((tid & 63) < 32) unsafeAtomicAdd(&pool[f], acc);
}

// K9: logits
__global__ void k9_logits(const float* __restrict__ pool, const float* __restrict__ lin_w,
                          const float* __restrict__ lin_b, float* __restrict__ out) {
    int j = threadIdx.x;
    if (j < 2) {
        float s = 0.f;
        for (int f = 0; f < 32; f++) s += (pool[f] * (1.0f / NN)) * lin_w[f * 2 + j];
        out[j] = s + lin_b[j];
    }
}

extern "C" void kernel_launch(void* const* d_in, const int* in_sizes, int n_in,
                              void* d_out, int out_size, void* d_ws, size_t ws_size,
                              hipStream_t stream) {
    const float* x    = (const float*)d_in[0];
    const int*   ei   = (const int*)d_in[1];
    const float* W1   = (const float*)d_in[2];
    const float* aS1  = (const float*)d_in[3];
    const float* aD1  = (const float*)d_in[4];
    const float* b1   = (const float*)d_in[5];
    const float* W2   = (const float*)d_in[6];
    const float* aS2  = (const float*)d_in[7];
    const float* aD2  = (const float*)d_in[8];
    const float* b2   = (const float*)d_in[9];
    const float* linw = (const float*)d_in[10];
    const float* linb = (const float*)d_in[11];

    float*          ws    = (float*)d_ws;
    float*          xa    = ws + OFF_XA;
    float*          ad1   = ws + OFF_AD1;
    float*          as2   = ws + OFF_AS2;
    float*          adi   = ws + OFF_ADI;
    __half*         xw2h  = (__half*)(ws + OFF_XW2H);
    int*            offs  = (int*)(ws + OFF_OFFS);
    unsigned short* rank  = (unsigned short*)(ws + OFF_RANK);
    int*            ed    = (int*)(ws + OFF_EDATA);
    float*          ppart = ws + OFF_POOLPART;
    int*            deg   = (int*)(ws + OFF_DEG);
    float*          pool  = ws + OFF_POOL;
    int*            bsum  = (int*)(ws + OFF_BSUM);

    float* logits = (float*)d_out;
    float* attn   = (float*)d_out + 2;

    k1_att1<<<(NN + 255) / 256, 256, 0, stream>>>(x, W1, aS1, aD1, xa, ad1,
                                                  (float4*)(ws + ZERO_START));
    kc1_deg<<<(ET + 255) / 256, 256, 0, stream>>>(ei, deg, rank);
    kc2a<<<SCAN_NB, 256, 0, stream>>>(deg, bsum);
    kc2c<<<SCAN_NB, 256, 0, stream>>>(deg, bsum, offs);
    kc3_fill<<<(ET + 255) / 256, 256, 0, stream>>>(ei, offs, rank, ed);
    k4ab<<<NN / 4, 256, 0, stream>>>(offs, ed, xa, ad1, W1, b1, W2,
                                     aS2, aD2, xw2h, as2, adi);
    k6_conv2<<<NN / 8, 256, 0, stream>>>(offs, ed, (const __half2*)xw2h, as2, adi,
                                         b2, ppart);
    k7_attn<<<(ET + 255) / 256, 256, 0, stream>>>(ei, as2, adi, attn);
    k8_pool<<<256, 256, 0, stream>>>(ppart, pool);
    k9_logits<<<1, 64, 0, stream>>>(pool, linw, linb, logits);
}